// Round 1
// baseline (152.941 us; speedup 1.0000x reference)
//
#include <hip/hip_runtime.h>
#include <hip/hip_bf16.h>
#include <cstddef>

// Problem constants
#define B_DIM 64
#define C_DIM 256
#define T_DIM 120
#define V_DIM 25
#define TV    (T_DIM * V_DIM)   // 3000
#define CTILE 16

// ---------------------------------------------------------------------------
// Kernel A: fold the two linear layers.
//   WcT[i][c] = sum_j Wo[c][j] * Wv[j][i]      (transposed combined weight)
//   bc[c]     = sum_i Wo[c][i] * bv[i] + bo[c]
// grid = 256 blocks (one per c), block = 256 threads (one per i).
// ---------------------------------------------------------------------------
__global__ __launch_bounds__(256) void make_wc(
    const float* __restrict__ Wo, const float* __restrict__ Wv,
    const float* __restrict__ bv, const float* __restrict__ bo,
    float* __restrict__ WcT, float* __restrict__ bc) {
  const int c = blockIdx.x;
  const int i = threadIdx.x;

  float acc = 0.0f;
  for (int j = 0; j < C_DIM; ++j) {
    acc = fmaf(Wo[c * C_DIM + j], Wv[j * C_DIM + i], acc);
  }
  WcT[i * C_DIM + c] = acc;

  __shared__ float red[C_DIM];
  red[i] = Wo[c * C_DIM + i] * bv[i];
  __syncthreads();
  for (int s = 128; s > 0; s >>= 1) {
    if (i < s) red[i] += red[i + s];
    __syncthreads();
  }
  if (i == 0) bc[c] = red[0] + bo[c];
}

// ---------------------------------------------------------------------------
// Kernel B: fused ov-compute + streaming add.
//   ov[b][c][t] = bc[c] + sum_i WcT[i][c] * y[b][i][t]
//   z[b][c][t][v] = x[b][c][t][v] + ov[b][c][t]
// grid = (B, C/CTILE) ; block = 256 threads.
// Phase 1: threads 0..119 compute c-tile half 0 (8 c's), 128..247 half 1.
// Phase 2: stream 16*3000 contiguous floats as float4.
// ---------------------------------------------------------------------------
__global__ __launch_bounds__(256) void fused_main(
    const float* __restrict__ x, const float* __restrict__ y,
    const float* __restrict__ WcT, const float* __restrict__ bc,
    float* __restrict__ z) {
  const int b  = blockIdx.x;
  const int c0 = blockIdx.y * CTILE;
  const int tid = threadIdx.x;

  __shared__ float ov[CTILE][T_DIM + 4];  // padded; [cl][120] may be read but never selected

  // ---- Phase 1: compute ov tile ----
  {
    const int chalf = tid >> 7;     // 0 or 1
    const int t = tid & 127;
    if (t < T_DIM) {
      const int cb = c0 + chalf * 8;
      float acc[8];
#pragma unroll
      for (int cl = 0; cl < 8; ++cl) acc[cl] = bc[cb + cl];
      const float* yb = y + (size_t)b * C_DIM * T_DIM + t;
      for (int i = 0; i < C_DIM; ++i) {
        const float yv = yb[(size_t)i * T_DIM];
        const float4* wr = (const float4*)(WcT + i * C_DIM + cb);
        const float4 w0 = wr[0];
        const float4 w1 = wr[1];
        acc[0] = fmaf(w0.x, yv, acc[0]);
        acc[1] = fmaf(w0.y, yv, acc[1]);
        acc[2] = fmaf(w0.z, yv, acc[2]);
        acc[3] = fmaf(w0.w, yv, acc[3]);
        acc[4] = fmaf(w1.x, yv, acc[4]);
        acc[5] = fmaf(w1.y, yv, acc[5]);
        acc[6] = fmaf(w1.z, yv, acc[6]);
        acc[7] = fmaf(w1.w, yv, acc[7]);
      }
#pragma unroll
      for (int cl = 0; cl < 8; ++cl) ov[chalf * 8 + cl][t] = acc[cl];
    }
  }
  __syncthreads();

  // ---- Phase 2: streaming z = x + ov ----
  const size_t base = ((size_t)b * C_DIM + c0) * TV;
  const float4* __restrict__ xin = (const float4*)(x + base);
  float4* __restrict__ zout = (float4*)(z + base);
  const int NF4 = CTILE * (TV / 4);  // 12000 float4 per block

  for (int idx = tid; idx < NF4; idx += 256) {
    const int cl  = idx / 750;            // 750 float4 per c-row (3000 floats)
    const int p4  = idx - cl * 750;
    const int pos = p4 * 4;               // float offset within the c-row
    const int t0  = pos / 25;             // V = 25
    const int r   = pos - t0 * 25;        // 0..24

    const float4 xv = xin[idx];
    const float a0 = ov[cl][t0];
    const float a1 = ov[cl][t0 + 1];      // only selected when valid (see proof in notes)

    float4 o;
    o.x = xv.x + a0;                      // r <= 24 -> always t0
    o.y = xv.y + ((r + 1 < 25) ? a0 : a1);
    o.z = xv.z + ((r + 2 < 25) ? a0 : a1);
    o.w = xv.w + ((r + 3 < 25) ? a0 : a1);
    zout[idx] = o;
  }
}

// ---------------------------------------------------------------------------
extern "C" void kernel_launch(void* const* d_in, const int* in_sizes, int n_in,
                              void* d_out, int out_size, void* d_ws, size_t ws_size,
                              hipStream_t stream) {
  // setup_inputs order: x, y, Wq, bq, Wk, bk, Wv, bv, Wo, bo
  const float* x  = (const float*)d_in[0];
  const float* y  = (const float*)d_in[1];
  const float* Wv = (const float*)d_in[6];
  const float* bv = (const float*)d_in[7];
  const float* Wo = (const float*)d_in[8];
  const float* bo = (const float*)d_in[9];
  float* z = (float*)d_out;

  float* WcT = (float*)d_ws;                       // 256*256 floats = 256 KiB
  float* bc  = WcT + C_DIM * C_DIM;                // 256 floats

  make_wc<<<dim3(C_DIM), dim3(C_DIM), 0, stream>>>(Wo, Wv, bv, bo, WcT, bc);

  dim3 grid(B_DIM, C_DIM / CTILE);
  fused_main<<<grid, dim3(256), 0, stream>>>(x, y, WcT, bc, z);
}

// Round 2
// 111.892 us; speedup vs baseline: 1.3669x; 1.3669x over previous
//
#include <hip/hip_runtime.h>
#include <cstddef>

// Problem constants
#define B_DIM 64
#define C_DIM 256
#define T_DIM 120
#define V_DIM 25
#define TV    3000            // T_DIM * V_DIM
#define CTILE 16

typedef float f4v __attribute__((ext_vector_type(4)));

// ---------------------------------------------------------------------------
// Kernel A: fold the two linear layers.
//   WcT[i][c] = sum_j Wo[c][j] * Wv[j][i]
//   bc[c]     = sum_i Wo[c][i] * bv[i] + bo[c]
// grid = 256 (one per c), block = 256 (one per i).
// ---------------------------------------------------------------------------
__global__ __launch_bounds__(256) void make_wc(
    const float* __restrict__ Wo, const float* __restrict__ Wv,
    const float* __restrict__ bv, const float* __restrict__ bo,
    float* __restrict__ WcT, float* __restrict__ bc) {
  const int c = blockIdx.x;
  const int i = threadIdx.x;

  float acc = 0.0f;
#pragma unroll 8
  for (int j = 0; j < C_DIM; ++j) {
    acc = fmaf(Wo[c * C_DIM + j], Wv[j * C_DIM + i], acc);
  }
  WcT[i * C_DIM + c] = acc;

  __shared__ float red[C_DIM];
  red[i] = Wo[c * C_DIM + i] * bv[i];
  __syncthreads();
  for (int s = 128; s > 0; s >>= 1) {
    if (i < s) red[i] += red[i + s];
    __syncthreads();
  }
  if (i == 0) bc[c] = red[0] + bo[c];
}

// ---------------------------------------------------------------------------
// Kernel B: ov[b*C + c][t] = bc[c] + sum_i WcT[i][c] * y[b][i][t]
// grid = (B, C/CTILE), block = 256.
// threads 0..119 -> c in [c0, c0+8); threads 128..247 -> c in [c0+8, c0+16).
// i-loop unrolled x8 with batched loads to amortize memory latency.
// ---------------------------------------------------------------------------
__global__ __launch_bounds__(256) void ov_kernel(
    const float* __restrict__ y, const float* __restrict__ WcT,
    const float* __restrict__ bc, float* __restrict__ ov) {
  const int b   = blockIdx.x;
  const int c0  = blockIdx.y * CTILE;
  const int tid = threadIdx.x;
  const int chalf = tid >> 7;      // wave-uniform (wave = tid/64)
  const int t     = tid & 127;
  if (t >= T_DIM) return;

  const int cb = __builtin_amdgcn_readfirstlane(c0 + chalf * 8);

  float acc[8];
#pragma unroll
  for (int cl = 0; cl < 8; ++cl) acc[cl] = bc[cb + cl];

  const float* yb = y + (size_t)b * C_DIM * T_DIM + t;

  for (int i = 0; i < C_DIM; i += 8) {
    float yv[8];
#pragma unroll
    for (int u = 0; u < 8; ++u) yv[u] = yb[(size_t)(i + u) * T_DIM];
#pragma unroll
    for (int u = 0; u < 8; ++u) {
      const f4v* wr = (const f4v*)(WcT + (i + u) * C_DIM + cb);
      const f4v w0 = wr[0];
      const f4v w1 = wr[1];
      acc[0] = fmaf(w0.x, yv[u], acc[0]);
      acc[1] = fmaf(w0.y, yv[u], acc[1]);
      acc[2] = fmaf(w0.z, yv[u], acc[2]);
      acc[3] = fmaf(w0.w, yv[u], acc[3]);
      acc[4] = fmaf(w1.x, yv[u], acc[4]);
      acc[5] = fmaf(w1.y, yv[u], acc[5]);
      acc[6] = fmaf(w1.z, yv[u], acc[6]);
      acc[7] = fmaf(w1.w, yv[u], acc[7]);
    }
  }

  float* ovp = ov + ((size_t)b * C_DIM + cb) * T_DIM + t;
#pragma unroll
  for (int cl = 0; cl < 8; ++cl) ovp[(size_t)cl * T_DIM] = acc[cl];
}

// ---------------------------------------------------------------------------
// Kernel C: streaming z[b][c][t][v] = x[...] + ov[b*C+c][t]
// Pure grid-stride float4 streamer; ov is hot in L1/L2.
// ---------------------------------------------------------------------------
__global__ __launch_bounds__(256) void add_kernel(
    const float* __restrict__ x, const float* __restrict__ ov,
    float* __restrict__ z) {
  const int NF4    = B_DIM * C_DIM * TV / 4;  // 12,288,000 float4
  const int stride = gridDim.x * 256;
  const f4v* __restrict__ xin  = (const f4v*)x;
  f4v* __restrict__       zout = (f4v*)z;

  for (int idx = blockIdx.x * 256 + threadIdx.x; idx < NF4; idx += stride) {
    const int pos    = idx * 4;             // global float offset (< 2^31)
    const int row    = pos / TV;            // = b*C_DIM + c
    const int within = pos - row * TV;
    const int t0     = within / V_DIM;
    const int r      = within - t0 * V_DIM; // 0..24

    const float* ovr = ov + (size_t)row * T_DIM;
    const float a0 = ovr[t0];
    const int   t1 = (t0 < T_DIM - 1) ? (t0 + 1) : t0;
    const float a1 = ovr[t1];

    f4v xv = __builtin_nontemporal_load(&xin[idx]);
    f4v o;
    o.x = xv.x + a0;
    o.y = xv.y + ((r + 1 < V_DIM) ? a0 : a1);
    o.z = xv.z + ((r + 2 < V_DIM) ? a0 : a1);
    o.w = xv.w + ((r + 3 < V_DIM) ? a0 : a1);
    __builtin_nontemporal_store(o, &zout[idx]);
  }
}

// ---------------------------------------------------------------------------
extern "C" void kernel_launch(void* const* d_in, const int* in_sizes, int n_in,
                              void* d_out, int out_size, void* d_ws, size_t ws_size,
                              hipStream_t stream) {
  // setup_inputs order: x, y, Wq, bq, Wk, bk, Wv, bv, Wo, bo
  const float* x  = (const float*)d_in[0];
  const float* y  = (const float*)d_in[1];
  const float* Wv = (const float*)d_in[6];
  const float* bv = (const float*)d_in[7];
  const float* Wo = (const float*)d_in[8];
  const float* bo = (const float*)d_in[9];
  float* z = (float*)d_out;

  // ws layout: ov (B*C*T floats = 7.86 MB) | WcT (256 KiB) | bc (1 KiB)
  float* ov  = (float*)d_ws;
  float* WcT = ov + (size_t)B_DIM * C_DIM * T_DIM;
  float* bc  = WcT + C_DIM * C_DIM;

  make_wc<<<dim3(C_DIM), dim3(C_DIM), 0, stream>>>(Wo, Wv, bv, bo, WcT, bc);

  ov_kernel<<<dim3(B_DIM, C_DIM / CTILE), dim3(256), 0, stream>>>(y, WcT, bc, ov);

  add_kernel<<<dim3(2048), dim3(256), 0, stream>>>(x, ov, z);
}

// Round 3
// 97.027 us; speedup vs baseline: 1.5763x; 1.1532x over previous
//
#include <hip/hip_runtime.h>
#include <cstddef>

// Problem constants
#define B_DIM 64
#define C_DIM 256
#define T_DIM 120
#define V_DIM 25
#define TV    3000            // T_DIM * V_DIM
#define CTILE 16

// add_kernel geometry (compile-time trip count: NF4 / STRIDE must be exact)
#define ABLOCKS 1920
#define ATHREADS 256
#define ASTRIDE (ABLOCKS * ATHREADS)          // 491520
#define NF4 (B_DIM * C_DIM * TV / 4)          // 12,288,000
#define AITERS (NF4 / ASTRIDE)                // 25 exactly

typedef float f4v __attribute__((ext_vector_type(4)));

// ---------------------------------------------------------------------------
// Kernel A: fold the two linear layers.
//   WcT[i][c] = sum_j Wo[c][j] * Wv[j][i]
//   bc[c]     = sum_i Wo[c][i] * bv[i] + bo[c]
// grid = 256 (one per c), block = 256 (one per i).
// ---------------------------------------------------------------------------
__global__ __launch_bounds__(256) void make_wc(
    const float* __restrict__ Wo, const float* __restrict__ Wv,
    const float* __restrict__ bv, const float* __restrict__ bo,
    float* __restrict__ WcT, float* __restrict__ bc) {
  const int c = blockIdx.x;
  const int i = threadIdx.x;

  float acc = 0.0f;
#pragma unroll 8
  for (int j = 0; j < C_DIM; ++j) {
    acc = fmaf(Wo[c * C_DIM + j], Wv[j * C_DIM + i], acc);
  }
  WcT[i * C_DIM + c] = acc;

  __shared__ float red[C_DIM];
  red[i] = Wo[c * C_DIM + i] * bv[i];
  __syncthreads();
  for (int s = 128; s > 0; s >>= 1) {
    if (i < s) red[i] += red[i + s];
    __syncthreads();
  }
  if (i == 0) bc[c] = red[0] + bo[c];
}

// ---------------------------------------------------------------------------
// Kernel B: ov[b*C + c][t] = bc[c] + sum_i WcT[i][c] * y[b][i][t]
// grid = (B, C/CTILE), block = 256.
// threads 0..119 -> c in [c0, c0+8); threads 128..247 -> c in [c0+8, c0+16).
// y loads are coalesced (lane index = t, contiguous); WcT loads wave-uniform.
// ---------------------------------------------------------------------------
__global__ __launch_bounds__(256) void ov_kernel(
    const float* __restrict__ y, const float* __restrict__ WcT,
    const float* __restrict__ bc, float* __restrict__ ov) {
  const int b   = blockIdx.x;
  const int c0  = blockIdx.y * CTILE;
  const int tid = threadIdx.x;
  const int chalf = tid >> 7;      // wave-uniform (wave = tid/64)
  const int t     = tid & 127;
  if (t >= T_DIM) return;

  const int cb = __builtin_amdgcn_readfirstlane(c0 + chalf * 8);

  float acc[8];
#pragma unroll
  for (int cl = 0; cl < 8; ++cl) acc[cl] = bc[cb + cl];

  const float* yb = y + (size_t)b * C_DIM * T_DIM + t;

  for (int i = 0; i < C_DIM; i += 8) {
    float yv[8];
#pragma unroll
    for (int u = 0; u < 8; ++u) yv[u] = yb[(size_t)(i + u) * T_DIM];
#pragma unroll
    for (int u = 0; u < 8; ++u) {
      const f4v* wr = (const f4v*)(WcT + (i + u) * C_DIM + cb);
      const f4v w0 = wr[0];
      const f4v w1 = wr[1];
      acc[0] = fmaf(w0.x, yv[u], acc[0]);
      acc[1] = fmaf(w0.y, yv[u], acc[1]);
      acc[2] = fmaf(w0.z, yv[u], acc[2]);
      acc[3] = fmaf(w0.w, yv[u], acc[3]);
      acc[4] = fmaf(w1.x, yv[u], acc[4]);
      acc[5] = fmaf(w1.y, yv[u], acc[5]);
      acc[6] = fmaf(w1.z, yv[u], acc[6]);
      acc[7] = fmaf(w1.w, yv[u], acc[7]);
    }
  }

  float* ovp = ov + ((size_t)b * C_DIM + cb) * T_DIM + t;
#pragma unroll
  for (int cl = 0; cl < 8; ++cl) ovp[(size_t)cl * T_DIM] = acc[cl];
}

// ---------------------------------------------------------------------------
// Kernel C: streaming z[b][c][t][v] = x[...] + ov[b*C+c][t]
// Plain load for x (keep it L3-resident across graph replays);
// nontemporal store for z (don't evict x from L3).
// Compile-time trip count (25) -> compiler unrolls & keeps loads in flight.
// ---------------------------------------------------------------------------
__global__ __launch_bounds__(ATHREADS) void add_kernel(
    const float* __restrict__ x, const float* __restrict__ ov,
    float* __restrict__ z) {
  const f4v* __restrict__ xin  = (const f4v*)x;
  f4v* __restrict__       zout = (f4v*)z;

  int idx = blockIdx.x * ATHREADS + threadIdx.x;
#pragma unroll 5
  for (int u = 0; u < AITERS; ++u, idx += ASTRIDE) {
    const int pos    = idx * 4;             // global float offset (< 2^31)
    const int row    = pos / TV;            // = b*C_DIM + c   (magic mul)
    const int within = pos - row * TV;
    const int t0     = within / V_DIM;
    const int r      = within - t0 * V_DIM; // 0..24

    const float* ovr = ov + (size_t)row * T_DIM;
    const float a0 = ovr[t0];
    const float a1 = ovr[(t0 < T_DIM - 1) ? (t0 + 1) : t0];

    const f4v xv = xin[idx];
    f4v o;
    o.x = xv.x + a0;
    o.y = xv.y + ((r + 1 < V_DIM) ? a0 : a1);
    o.z = xv.z + ((r + 2 < V_DIM) ? a0 : a1);
    o.w = xv.w + ((r + 3 < V_DIM) ? a0 : a1);
    __builtin_nontemporal_store(o, &zout[idx]);
  }
}

// ---------------------------------------------------------------------------
extern "C" void kernel_launch(void* const* d_in, const int* in_sizes, int n_in,
                              void* d_out, int out_size, void* d_ws, size_t ws_size,
                              hipStream_t stream) {
  // setup_inputs order: x, y, Wq, bq, Wk, bk, Wv, bv, Wo, bo
  const float* x  = (const float*)d_in[0];
  const float* y  = (const float*)d_in[1];
  const float* Wv = (const float*)d_in[6];
  const float* bv = (const float*)d_in[7];
  const float* Wo = (const float*)d_in[8];
  const float* bo = (const float*)d_in[9];
  float* z = (float*)d_out;

  // ws layout: ov (B*C*T floats = 7.86 MB) | WcT (256 KiB) | bc (1 KiB)
  float* ov  = (float*)d_ws;
  float* WcT = ov + (size_t)B_DIM * C_DIM * T_DIM;
  float* bc  = WcT + C_DIM * C_DIM;

  make_wc<<<dim3(C_DIM), dim3(C_DIM), 0, stream>>>(Wo, Wv, bv, bo, WcT, bc);

  ov_kernel<<<dim3(B_DIM, C_DIM / CTILE), dim3(256), 0, stream>>>(y, WcT, bc, ov);

  add_kernel<<<dim3(ABLOCKS), dim3(ATHREADS), 0, stream>>>(x, ov, z);
}